// Round 8
// baseline (368.586 us; speedup 1.0000x reference)
//
#include <hip/hip_runtime.h>

// DilateAttention: B=4, d=384 (12 heads x 32), H=W=64, 3x3 taps, dilation 2, pad 2.
// f32 in / f32 out. Round 8: R4's branchless register-gather shape, but each
// thread = 2 x-adjacent pixels x 16 channels (float2 loads, half the VMEM
// instructions, same 3072 waves). Channel halves = lanes +/-32 in the same
// wave; logits summed via shfl_xor(32); softmax redundant per half.

#define HD   32
#define NHD  12
#define DDIM 384
#define HH   64
#define WW   64
#define HWSZ 4096
#define SCALEF 0.17677669529663687f  // 1/sqrt(32)

// block = 256: tid = xpair(5b) | half(1b) | row(2b). grid = 16 ygroups * 48 heads.
__global__ __launch_bounds__(256, 4) void dilate_attn(const float* __restrict__ q,
                                                      const float* __restrict__ k,
                                                      const float* __restrict__ v,
                                                      float* __restrict__ out) {
    const int tid = threadIdx.x;
    const int xp  = tid & 31;          // x-pair index -> pixels 2*xp, 2*xp+1
    const int h   = (tid >> 5) & 1;    // channel half (0: ch 0-15, 1: ch 16-31)
    const int r   = tid >> 6;          // y row within group, 0..3

    // z = yg*48 + bh: all rows of head (b,n) share z%8 -> same XCD slot (tap-row L2 reuse)
    const int z   = blockIdx.x;
    const int bh  = z % 48;            // b*NHD + n
    const int yg  = z / 48;            // 0..15
    const int b   = bh / NHD;
    const int n   = bh - b * NHD;
    const int y   = yg * 4 + r;
    const int xq  = xp * 2;

    const size_t half_base = (size_t)(b * DDIM + n * HD + h * 16) * HWSZ;
    const int pix = y * WW + xq;

    // 9 tap offsets (pair-aligned, xo even), clamped to center when OOB.
    int  toff[9];
    bool tval[9];
#pragma unroll
    for (int di = 0; di < 3; ++di) {
        int yy = y + 2 * di - 2;
        bool vy = (yy >= 0) && (yy < HH);
#pragma unroll
        for (int p = 0; p < 3; ++p) {
            int xo = xq + 2 * p - 2;
            bool ok = vy && (xo >= 0) && (xo < WW);   // xo even: pair in/out together
            tval[di * 3 + p] = ok;
            toff[di * 3 + p] = ok ? (yy * WW + xo) : pix;
        }
    }

    // ---------------- preload q (both pixels, 16 ch) ----------------
    const float* qb = q + half_base + pix;
    float2 qreg[16];
#pragma unroll
    for (int c = 0; c < 16; ++c) qreg[c] = *(const float2*)(qb + (size_t)c * HWSZ);

    // ---------------- Phase 1: partial logits over 16 ch, float2 taps ----------------
    const float* kb = k + half_base;
    float l0[9], l1[9];
#pragma unroll
    for (int t = 0; t < 9; ++t) {
        const float* kt = kb + toff[t];
        float a0x = 0.f, a0y = 0.f, a1x = 0.f, a1y = 0.f;
#pragma unroll
        for (int c = 0; c < 16; c += 2) {
            float2 k0 = *(const float2*)(kt + (size_t)c * HWSZ);
            float2 k1 = *(const float2*)(kt + (size_t)(c + 1) * HWSZ);
            a0x += qreg[c].x * k0.x;     a0y += qreg[c].y * k0.y;
            a1x += qreg[c + 1].x * k1.x; a1y += qreg[c + 1].y * k1.y;
        }
        l0[t] = a0x + a1x;   // pixel xq,   this half's 16 ch
        l1[t] = a0y + a1y;   // pixel xq+1, this half's 16 ch
    }

    // ---------------- cross-half reduction (lane +/- 32, same wave) ----------------
#pragma unroll
    for (int t = 0; t < 9; ++t) {
        l0[t] += __shfl_xor(l0[t], 32, 64);
        l1[t] += __shfl_xor(l1[t], 32, 64);
        l0[t] = tval[t] ? (l0[t] * SCALEF) : 0.f;   // zero-pad taps: logit exactly 0
        l1[t] = tval[t] ? (l1[t] * SCALEF) : 0.f;
    }

    // ---------------- softmax over 9, per pixel (redundant per half) ----------------
    float m0 = l0[0], m1 = l1[0];
#pragma unroll
    for (int t = 1; t < 9; ++t) { m0 = fmaxf(m0, l0[t]); m1 = fmaxf(m1, l1[t]); }
    float w0[9], w1[9], s0 = 0.f, s1 = 0.f;
#pragma unroll
    for (int t = 0; t < 9; ++t) {
        w0[t] = __expf(l0[t] - m0); s0 += w0[t];
        w1[t] = __expf(l1[t] - m1); s1 += w1[t];
    }
    float i0 = 1.0f / s0, i1 = 1.0f / s1;
#pragma unroll
    for (int t = 0; t < 9; ++t) {
        w0[t] = tval[t] ? (w0[t] * i0) : 0.f;   // clamped v-load must not contribute
        w1[t] = tval[t] ? (w1[t] * i1) : 0.f;
    }

    // ---------------- Phase 2: weighted V over this half's 16 ch ----------------
    const float* vb = v + half_base;
    float o0[16], o1[16];
#pragma unroll
    for (int c = 0; c < 16; ++c) { o0[c] = 0.f; o1[c] = 0.f; }
#pragma unroll
    for (int t = 0; t < 9; ++t) {
        const float* vt = vb + toff[t];
        float wt0 = w0[t], wt1 = w1[t];
#pragma unroll
        for (int c = 0; c < 16; ++c) {
            float2 vv = *(const float2*)(vt + (size_t)c * HWSZ);
            o0[c] += wt0 * vv.x;
            o1[c] += wt1 * vv.y;
        }
    }

    // ---------------- store: lane pair (h=0,h=1) covers the full 128-B line ----------------
    float* ob0 = out + ((size_t)(b * HH + y) * WW + xq) * DDIM + n * HD + h * 16;
    float* ob1 = ob0 + DDIM;   // pixel xq+1
    *(float4*)(ob0)      = make_float4(o0[0],  o0[1],  o0[2],  o0[3]);
    *(float4*)(ob0 + 4)  = make_float4(o0[4],  o0[5],  o0[6],  o0[7]);
    *(float4*)(ob0 + 8)  = make_float4(o0[8],  o0[9],  o0[10], o0[11]);
    *(float4*)(ob0 + 12) = make_float4(o0[12], o0[13], o0[14], o0[15]);
    *(float4*)(ob1)      = make_float4(o1[0],  o1[1],  o1[2],  o1[3]);
    *(float4*)(ob1 + 4)  = make_float4(o1[4],  o1[5],  o1[6],  o1[7]);
    *(float4*)(ob1 + 8)  = make_float4(o1[8],  o1[9],  o1[10], o1[11]);
    *(float4*)(ob1 + 12) = make_float4(o1[12], o1[13], o1[14], o1[15]);
}

extern "C" void kernel_launch(void* const* d_in, const int* in_sizes, int n_in,
                              void* d_out, int out_size, void* d_ws, size_t ws_size,
                              hipStream_t stream) {
    const float* q = (const float*)d_in[0];
    const float* k = (const float*)d_in[1];
    const float* v = (const float*)d_in[2];
    float* out = (float*)d_out;
    // grid = 16 ygroups * 48 (b,head) = 768 blocks, 256 threads (3072 waves)
    hipLaunchKernelGGL(dilate_attn, dim3(768), dim3(256), 0, stream, q, k, v, out);
}

// Round 9
// 208.389 us; speedup vs baseline: 1.7687x; 1.7687x over previous
//
#include <hip/hip_runtime.h>

// DilateAttention: B=4, d=384 (12 heads x 32), H=W=64, 3x3 taps, dilation 2, pad 2.
// f32 in / f32 out. Round 9 = Round 8 (2 px x 16 ch / thread, float2 taps,
// shfl cross-half reduce) with the spill bug fixed: no min-waves clamp
// (R8's __launch_bounds__(256,4) forced VGPR=64 -> 445 MB scratch writes),
// and phase 2 split into two 8-channel passes to cut peak live registers.

#define HD   32
#define NHD  12
#define DDIM 384
#define HH   64
#define WW   64
#define HWSZ 4096
#define SCALEF 0.17677669529663687f  // 1/sqrt(32)

// block = 256: tid = xpair(5b) | half(1b) | row(2b). grid = 16 ygroups * 48 heads.
__global__ __launch_bounds__(256) void dilate_attn(const float* __restrict__ q,
                                                   const float* __restrict__ k,
                                                   const float* __restrict__ v,
                                                   float* __restrict__ out) {
    const int tid = threadIdx.x;
    const int xp  = tid & 31;          // x-pair index -> pixels 2*xp, 2*xp+1
    const int h   = (tid >> 5) & 1;    // channel half (0: ch 0-15, 1: ch 16-31)
    const int r   = tid >> 6;          // y row within group, 0..3

    // z = yg*48 + bh: all rows of head (b,n) share z%8 -> same XCD slot (tap-row L2 reuse)
    const int z   = blockIdx.x;
    const int bh  = z % 48;            // b*NHD + n
    const int yg  = z / 48;            // 0..15
    const int b   = bh / NHD;
    const int n   = bh - b * NHD;
    const int y   = yg * 4 + r;
    const int xq  = xp * 2;

    const size_t half_base = (size_t)(b * DDIM + n * HD + h * 16) * HWSZ;
    const int pix = y * WW + xq;

    // 9 tap offsets (pair-aligned, xo even), clamped to center when OOB.
    int  toff[9];
    bool tval[9];
#pragma unroll
    for (int di = 0; di < 3; ++di) {
        int yy = y + 2 * di - 2;
        bool vy = (yy >= 0) && (yy < HH);
#pragma unroll
        for (int p = 0; p < 3; ++p) {
            int xo = xq + 2 * p - 2;
            bool ok = vy && (xo >= 0) && (xo < WW);   // xo even: pair in/out together
            tval[di * 3 + p] = ok;
            toff[di * 3 + p] = ok ? (yy * WW + xo) : pix;
        }
    }

    // ---------------- preload q (both pixels, 16 ch) ----------------
    const float* qb = q + half_base + pix;
    float2 qreg[16];
#pragma unroll
    for (int c = 0; c < 16; ++c) qreg[c] = *(const float2*)(qb + (size_t)c * HWSZ);

    // ---------------- Phase 1: partial logits over 16 ch, float2 taps ----------------
    const float* kb = k + half_base;
    float l0[9], l1[9];
#pragma unroll
    for (int t = 0; t < 9; ++t) {
        const float* kt = kb + toff[t];
        float a0x = 0.f, a0y = 0.f, a1x = 0.f, a1y = 0.f;
#pragma unroll
        for (int c = 0; c < 16; c += 2) {
            float2 k0 = *(const float2*)(kt + (size_t)c * HWSZ);
            float2 k1 = *(const float2*)(kt + (size_t)(c + 1) * HWSZ);
            a0x += qreg[c].x * k0.x;     a0y += qreg[c].y * k0.y;
            a1x += qreg[c + 1].x * k1.x; a1y += qreg[c + 1].y * k1.y;
        }
        l0[t] = a0x + a1x;   // pixel xq,   this half's 16 ch
        l1[t] = a0y + a1y;   // pixel xq+1, this half's 16 ch
    }

    // ---------------- cross-half reduction (lane +/- 32, same wave) ----------------
#pragma unroll
    for (int t = 0; t < 9; ++t) {
        l0[t] += __shfl_xor(l0[t], 32, 64);
        l1[t] += __shfl_xor(l1[t], 32, 64);
        l0[t] = tval[t] ? (l0[t] * SCALEF) : 0.f;   // zero-pad taps: logit exactly 0
        l1[t] = tval[t] ? (l1[t] * SCALEF) : 0.f;
    }

    // ---------------- softmax over 9, per pixel (redundant per half) ----------------
    float m0 = l0[0], m1 = l1[0];
#pragma unroll
    for (int t = 1; t < 9; ++t) { m0 = fmaxf(m0, l0[t]); m1 = fmaxf(m1, l1[t]); }
    float w0[9], w1[9], s0 = 0.f, s1 = 0.f;
#pragma unroll
    for (int t = 0; t < 9; ++t) {
        w0[t] = __expf(l0[t] - m0); s0 += w0[t];
        w1[t] = __expf(l1[t] - m1); s1 += w1[t];
    }
    float i0 = 1.0f / s0, i1 = 1.0f / s1;
#pragma unroll
    for (int t = 0; t < 9; ++t) {
        w0[t] = tval[t] ? (w0[t] * i0) : 0.f;   // clamped v-load must not contribute
        w1[t] = tval[t] ? (w1[t] * i1) : 0.f;
    }

    // ---------------- Phase 2: weighted V, two passes of 8 channels ----------------
    const float* vb = v + half_base;
    float* ob0 = out + ((size_t)(b * HH + y) * WW + xq) * DDIM + n * HD + h * 16;
    float* ob1 = ob0 + DDIM;   // pixel xq+1

#pragma unroll
    for (int pass = 0; pass < 2; ++pass) {
        const float* vp = vb + (size_t)(pass * 8) * HWSZ;
        float o0[8], o1[8];
#pragma unroll
        for (int c = 0; c < 8; ++c) { o0[c] = 0.f; o1[c] = 0.f; }
#pragma unroll
        for (int t = 0; t < 9; ++t) {
            const float* vt = vp + toff[t];
            float wt0 = w0[t], wt1 = w1[t];
#pragma unroll
            for (int c = 0; c < 8; ++c) {
                float2 vv = *(const float2*)(vt + (size_t)c * HWSZ);
                o0[c] += wt0 * vv.x;
                o1[c] += wt1 * vv.y;
            }
        }
        float* s0p = ob0 + pass * 8;
        float* s1p = ob1 + pass * 8;
        *(float4*)(s0p)     = make_float4(o0[0], o0[1], o0[2], o0[3]);
        *(float4*)(s0p + 4) = make_float4(o0[4], o0[5], o0[6], o0[7]);
        *(float4*)(s1p)     = make_float4(o1[0], o1[1], o1[2], o1[3]);
        *(float4*)(s1p + 4) = make_float4(o1[4], o1[5], o1[6], o1[7]);
    }
}

extern "C" void kernel_launch(void* const* d_in, const int* in_sizes, int n_in,
                              void* d_out, int out_size, void* d_ws, size_t ws_size,
                              hipStream_t stream) {
    const float* q = (const float*)d_in[0];
    const float* k = (const float*)d_in[1];
    const float* v = (const float*)d_in[2];
    float* out = (float*)d_out;
    // grid = 16 ygroups * 48 (b,head) = 768 blocks, 256 threads (3072 waves)
    hipLaunchKernelGGL(dilate_attn, dim3(768), dim3(256), 0, stream, q, k, v, out);
}